// Round 1
// baseline (10114.324 us; speedup 1.0000x reference)
//
#include <hip/hip_runtime.h>
#include <hip/hip_bf16.h>
#include <cmath>

// Problem dims (fixed)
#define B_SZ 64
#define T_SZ 2048
#define D_SZ 256
#define H_SZ 256
#define BT   (B_SZ * T_SZ)          // 131072
#define MAX_SKIP 4
#define CHUNK 32768                  // LSTM row chunk (gates buffer rows)

#define TILE_M 64
#define TILE_N 64
#define TILE_K 16

// ---------------------------------------------------------------------------
// Generic tiled fp32 GEMM: C = op(A @ B + bias)
// A: M x K row-major, B: K x N row-major, C: M x N row-major.
// batch via blockIdx.z with element strides bsA/bsB/bsC.
// All dims assumed divisible by tile sizes (true for this problem).
// ---------------------------------------------------------------------------
__global__ __launch_bounds__(256) void gemm_kernel(
    const float* __restrict__ A, const float* __restrict__ Bm,
    const float* __restrict__ bias, float* __restrict__ C,
    int M, int N, int K,
    long long bsA, long long bsB, long long bsC, int relu)
{
    __shared__ float As[TILE_K][TILE_M];
    __shared__ float Bs[TILE_K][TILE_N];

    const int bz = blockIdx.z;
    A  += (size_t)bz * bsA;
    Bm += (size_t)bz * bsB;
    C  += (size_t)bz * bsC;

    const int tid = threadIdx.x;
    const int tm = tid / 16, tn = tid % 16;
    const int row0 = blockIdx.x * TILE_M;
    const int col0 = blockIdx.y * TILE_N;

    float acc[4][4] = {};

    for (int k0 = 0; k0 < K; k0 += TILE_K) {
        // A tile: 64 rows x 16 k, transposed into As[k][m]
        {
            const int r = tid >> 2;            // 0..63
            const int kk = (tid & 3) << 2;     // 0,4,8,12
            const float4 v = *(const float4*)(A + (size_t)(row0 + r) * K + k0 + kk);
            As[kk + 0][r] = v.x; As[kk + 1][r] = v.y;
            As[kk + 2][r] = v.z; As[kk + 3][r] = v.w;
        }
        // B tile: 16 k x 64 cols
        {
            const int kk = tid >> 4;           // 0..15
            const int c = (tid & 15) << 2;     // 0..60
            const float4 v = *(const float4*)(Bm + (size_t)(k0 + kk) * N + col0 + c);
            *(float4*)&Bs[kk][c] = v;
        }
        __syncthreads();
        #pragma unroll
        for (int kk = 0; kk < TILE_K; ++kk) {
            const float4 a = *(const float4*)&As[kk][tm * 4];
            const float4 b = *(const float4*)&Bs[kk][tn * 4];
            const float av[4] = {a.x, a.y, a.z, a.w};
            const float bv[4] = {b.x, b.y, b.z, b.w};
            #pragma unroll
            for (int i = 0; i < 4; ++i)
                #pragma unroll
                for (int jj = 0; jj < 4; ++jj)
                    acc[i][jj] += av[i] * bv[jj];
        }
        __syncthreads();
    }

    #pragma unroll
    for (int i = 0; i < 4; ++i) {
        const int r = row0 + tm * 4 + i;
        #pragma unroll
        for (int jj = 0; jj < 4; ++jj) {
            const int c = col0 + tn * 4 + jj;
            float v = acc[i][jj];
            if (bias) v += bias[c];
            if (relu) v = fmaxf(v, 0.0f);
            C[(size_t)r * N + c] = v;
        }
    }
}

// ---------------------------------------------------------------------------
// LSTM gates GEMM: gates[lr, c] = xs[n,:] @ Wih[c,:] (+ hstate[n,:] @ Whh[c,:]) + bih[c]+bhh[c]
// xs[n,:] gathered from h at (b*T + w*p + j)*H with n = b*nw + w.
// N-dim of the GEMM = 4H = 1024. K = H = 256 per source.
// ---------------------------------------------------------------------------
__global__ __launch_bounds__(256) void lstm_gates_kernel(
    const float* __restrict__ h, const float* __restrict__ hstate,
    const float* __restrict__ Wih, const float* __restrict__ Whh,
    const float* __restrict__ bih, const float* __restrict__ bhh,
    float* __restrict__ gates,
    int nw, int p, int j, int rowStart)
{
    __shared__ float As[TILE_K][TILE_M];
    __shared__ float Bs[TILE_K][TILE_N];   // Bs[k][c] = W[col0+c][k]

    const int tid = threadIdx.x;
    const int tm = tid / 16, tn = tid % 16;
    const int row0 = rowStart + blockIdx.x * TILE_M;
    const int col0 = blockIdx.y * TILE_N;

    float acc[4][4] = {};

    const int nsrc = hstate ? 2 : 1;
    for (int src = 0; src < nsrc; ++src) {
        const float* W = (src == 0) ? Wih : Whh;
        for (int k0 = 0; k0 < H_SZ; k0 += TILE_K) {
            // A tile
            {
                const int r = tid >> 2;
                const int kk = (tid & 3) << 2;
                const int n = row0 + r;
                const float* aptr;
                if (src == 0) {
                    const int b = n / nw, w = n % nw;
                    aptr = h + ((size_t)b * T_SZ + (size_t)w * p + j) * H_SZ + k0 + kk;
                } else {
                    aptr = hstate + (size_t)n * H_SZ + k0 + kk;
                }
                const float4 v = *(const float4*)aptr;
                As[kk + 0][r] = v.x; As[kk + 1][r] = v.y;
                As[kk + 2][r] = v.z; As[kk + 3][r] = v.w;
            }
            // B tile (transposed weight access): Bs[k][c] = W[(col0+c)*H + k0+k]
            {
                const int c = tid >> 2;            // 0..63
                const int kk = (tid & 3) << 2;     // 0,4,8,12
                const float4 v = *(const float4*)(W + (size_t)(col0 + c) * H_SZ + k0 + kk);
                Bs[kk + 0][c] = v.x; Bs[kk + 1][c] = v.y;
                Bs[kk + 2][c] = v.z; Bs[kk + 3][c] = v.w;
            }
            __syncthreads();
            #pragma unroll
            for (int kk = 0; kk < TILE_K; ++kk) {
                const float4 a = *(const float4*)&As[kk][tm * 4];
                const float4 b = *(const float4*)&Bs[kk][tn * 4];
                const float av[4] = {a.x, a.y, a.z, a.w};
                const float bv[4] = {b.x, b.y, b.z, b.w};
                #pragma unroll
                for (int i = 0; i < 4; ++i)
                    #pragma unroll
                    for (int jj = 0; jj < 4; ++jj)
                        acc[i][jj] += av[i] * bv[jj];
            }
            __syncthreads();
        }
    }

    #pragma unroll
    for (int i = 0; i < 4; ++i) {
        const int lr = blockIdx.x * TILE_M + tm * 4 + i;  // row local to chunk
        #pragma unroll
        for (int jj = 0; jj < 4; ++jj) {
            const int c = col0 + tn * 4 + jj;
            gates[(size_t)lr * (4 * H_SZ) + c] = acc[i][jj] + bih[c] + bhh[c];
        }
    }
}

// ---------------------------------------------------------------------------
// LSTM pointwise: apply gate nonlinearities, update states / write output.
// ---------------------------------------------------------------------------
__global__ __launch_bounds__(256) void lstm_pointwise_kernel(
    const float* __restrict__ gates,
    float* __restrict__ hstate, float* __restrict__ cstate,
    float* __restrict__ out,
    int rowStart, int rows, int nw, int p, int first, int last)
{
    const int idx = blockIdx.x * blockDim.x + threadIdx.x;
    if (idx >= rows * H_SZ) return;
    const int lr = idx / H_SZ, hc = idx % H_SZ;
    const int n = rowStart + lr;

    const float* g = gates + (size_t)lr * (4 * H_SZ);
    const float gi = g[hc];
    const float gf = g[hc + H_SZ];
    const float gg = g[hc + 2 * H_SZ];
    const float go = g[hc + 3 * H_SZ];

    const float c_prev = first ? 0.0f : cstate[(size_t)n * H_SZ + hc];
    const float si = 1.0f / (1.0f + expf(-gi));
    const float sf = 1.0f / (1.0f + expf(-gf));
    const float so = 1.0f / (1.0f + expf(-go));
    const float tg = tanhf(gg);
    const float c = sf * c_prev + si * tg;
    const float hv = so * tanhf(c);

    if (last) {
        const int b = n / nw, w = n % nw;
        out[((size_t)b * T_SZ + (size_t)w * p + (p - 1)) * H_SZ + hc] = hv;
    } else {
        cstate[(size_t)n * H_SZ + hc] = c;
        hstate[(size_t)n * H_SZ + hc] = hv;
    }
}

// ---------------------------------------------------------------------------
extern "C" void kernel_launch(void* const* d_in, const int* in_sizes, int n_in,
                              void* d_out, int out_size, void* d_ws, size_t ws_size,
                              hipStream_t stream)
{
    const float* x   = (const float*)d_in[0];
    const float* adj = (const float*)d_in[1];
    const float* Wg0 = (const float*)d_in[2];
    const float* bg0 = (const float*)d_in[3];
    const float* Wg1 = (const float*)d_in[4];
    const float* bg1 = (const float*)d_in[5];
    const float* Wih = (const float*)d_in[6];
    const float* Whh = (const float*)d_in[7];
    const float* bih = (const float*)d_in[8];
    const float* bhh = (const float*)d_in[9];
    float* out = (float*)d_out;

    float* ws = (float*)d_ws;
    float* support = ws;                                  // BT*H floats (134 MB)
    float* hstate  = ws + (size_t)BT * H_SZ;              // BT*H/2 floats (67 MB)
    float* cstate  = hstate + (size_t)BT * H_SZ / 2;      // BT*H/2 floats (67 MB)
    float* gates   = support;                             // alias: support dead after GCN

    const dim3 blk(256);

    // GCN layer 1: support = x @ Wg0 + bg0 ; out = relu(adj @ support[b])
    gemm_kernel<<<dim3(BT / TILE_M, H_SZ / TILE_N, 1), blk, 0, stream>>>(
        x, Wg0, bg0, support, BT, H_SZ, D_SZ, 0, 0, 0, 0);
    gemm_kernel<<<dim3(T_SZ / TILE_M, H_SZ / TILE_N, B_SZ), blk, 0, stream>>>(
        adj, support, nullptr, out, T_SZ, H_SZ, T_SZ,
        0, (long long)T_SZ * H_SZ, (long long)T_SZ * H_SZ, 1);

    // GCN layer 2
    gemm_kernel<<<dim3(BT / TILE_M, H_SZ / TILE_N, 1), blk, 0, stream>>>(
        out, Wg1, bg1, support, BT, H_SZ, H_SZ, 0, 0, 0, 0);
    gemm_kernel<<<dim3(T_SZ / TILE_M, H_SZ / TILE_N, B_SZ), blk, 0, stream>>>(
        adj, support, nullptr, out, T_SZ, H_SZ, T_SZ,
        0, (long long)T_SZ * H_SZ, (long long)T_SZ * H_SZ, 1);

    // Skip-LSTM passes (sequential, in-place on out)
    for (int p = 1; p <= MAX_SKIP; ++p) {
        const int nw = T_SZ / p;
        const int Nrows = B_SZ * nw;
        const float* Wih_p = Wih + (size_t)(p - 1) * 4 * H_SZ * H_SZ;
        const float* Whh_p = Whh + (size_t)(p - 1) * 4 * H_SZ * H_SZ;
        const float* bih_p = bih + (size_t)(p - 1) * 4 * H_SZ;
        const float* bhh_p = bhh + (size_t)(p - 1) * 4 * H_SZ;

        for (int j = 0; j < p; ++j) {
            const int first = (j == 0) ? 1 : 0;
            const int last  = (j == p - 1) ? 1 : 0;
            for (int rs = 0; rs < Nrows; rs += CHUNK) {
                const int rows = (Nrows - rs < CHUNK) ? (Nrows - rs) : CHUNK;
                lstm_gates_kernel<<<dim3(rows / TILE_M, (4 * H_SZ) / TILE_N, 1), blk, 0, stream>>>(
                    out, first ? nullptr : hstate,
                    Wih_p, Whh_p, bih_p, bhh_p,
                    gates, nw, p, j, rs);
                lstm_pointwise_kernel<<<dim3(rows, 1, 1), blk, 0, stream>>>(
                    gates, hstate, cstate, out, rs, rows, nw, p, first, last);
            }
        }
    }
}

// Round 2
// 2682.126 us; speedup vs baseline: 3.7710x; 3.7710x over previous
//
#include <hip/hip_runtime.h>
#include <hip/hip_bf16.h>

#define T2 2048
#define H2 256
#define BT2 131072          // B*T = 64*2048
#define MAXP 4

typedef __attribute__((ext_vector_type(8))) short bf16x8;
typedef __attribute__((ext_vector_type(4))) float f32x4;
typedef unsigned short u16;

__device__ __forceinline__ u16 f2bf(float f) {
    union { float f; unsigned u; } v; v.f = f;
    unsigned r = (v.u + 0x7FFFu + ((v.u >> 16) & 1u)) >> 16;
    return (u16)r;
}
__device__ __forceinline__ float bf2f(u16 h) {
    union { unsigned u; float f; } v; v.u = ((unsigned)h) << 16; return v.f;
}
__device__ __forceinline__ void async16(const void* g, void* l) {
    __builtin_amdgcn_global_load_lds((const __attribute__((address_space(1))) void*)g,
                                     (__attribute__((address_space(3))) void*)l, 16, 0, 0);
}
__device__ __forceinline__ float tanh_f(float x) {
    return 1.f - 2.f / (__expf(2.f * x) + 1.f);
}
__device__ __forceinline__ void split4(const float4 v, ushort4& hi, ushort4& lo) {
    hi.x = f2bf(v.x); lo.x = f2bf(v.x - bf2f(hi.x));
    hi.y = f2bf(v.y); lo.y = f2bf(v.y - bf2f(hi.y));
    hi.z = f2bf(v.z); lo.z = f2bf(v.z - bf2f(hi.z));
    hi.w = f2bf(v.w); lo.w = f2bf(v.w - bf2f(hi.w));
}

// ---------------------------------------------------------------------------
// GCN GEMM: C = op(A_f32 @ Bt_bf16^T + bias). A [M][K] f32 (reg-convert to
// bf16 at stage), Bt [N][K] bf16 (global_load_lds). 128x128 tile, 4 waves,
// 16x16x32 bf16 MFMA. Outputs: f32 row-major (Cf) and/or bf16 transposed
// St[b][col][t] (Ct; assumes M = 64*2048 layout).
// ---------------------------------------------------------------------------
__global__ __launch_bounds__(256) void gcn_gemm(
    const float* __restrict__ A, const u16* __restrict__ Bt,
    const float* __restrict__ bias,
    float* __restrict__ Cf, u16* __restrict__ Ct,
    int M, int N, int K,
    long long bsA, long long bsB, long long bsC, int relu)
{
    __shared__ __align__(16) u16 As[128][32];
    __shared__ __align__(16) u16 Bs[128][32];

    const int tid = threadIdx.x;
    const int wid = tid >> 6, lane = tid & 63;
    const int wr = wid >> 1, wc = wid & 1;
    const int row0 = blockIdx.x * 128, col0 = blockIdx.y * 128;
    const int bz = blockIdx.z;
    A  += (long long)bz * bsA;
    Bt += (long long)bz * bsB;

    // B staging (async, 16B/lane x2): row = q*64 + tid/4, k-elems (tid&3)*8
    const int sr = tid >> 2;
    const int skB = (tid & 3) << 3;
    const u16* Bg0 = Bt + (size_t)(col0 + sr) * K + skB;
    const u16* Bg1 = Bt + (size_t)(col0 + 64 + sr) * K + skB;
    char* ldsB = (char*)&Bs[0][0];
    const int wb = wid << 10;

    // A staging (f32 -> bf16 reg-convert): seg s: row = s*32 + tid/8, f4col = tid&7
    const float* Ag = A + (size_t)(row0 + (tid >> 3)) * K + ((tid & 7) << 2);
    const int arow = tid >> 3, acol = (tid & 7) << 2;

    f32x4 acc[4][4];
    #pragma unroll
    for (int i = 0; i < 4; ++i)
        #pragma unroll
        for (int j = 0; j < 4; ++j) acc[i][j] = (f32x4){0.f, 0.f, 0.f, 0.f};

    for (int k0 = 0; k0 < K; k0 += 32) {
        __syncthreads();
        async16(Bg0 + k0, ldsB + wb);
        async16(Bg1 + k0, ldsB + 4096 + wb);
        #pragma unroll
        for (int s = 0; s < 4; ++s) {
            const float4 v = *(const float4*)(Ag + (size_t)(s * 32) * K + k0);
            ushort4 h;
            h.x = f2bf(v.x); h.y = f2bf(v.y); h.z = f2bf(v.z); h.w = f2bf(v.w);
            *(ushort4*)&As[s * 32 + arow][acol] = h;
        }
        __syncthreads();
        const int mb = lane & 15, kb = (lane >> 4) << 3;
        bf16x8 a[4], b[4];
        #pragma unroll
        for (int i = 0; i < 4; ++i) a[i] = *(const bf16x8*)&As[wr * 64 + i * 16 + mb][kb];
        #pragma unroll
        for (int j = 0; j < 4; ++j) b[j] = *(const bf16x8*)&Bs[wc * 64 + j * 16 + mb][kb];
        #pragma unroll
        for (int i = 0; i < 4; ++i)
            #pragma unroll
            for (int j = 0; j < 4; ++j)
                acc[i][j] = __builtin_amdgcn_mfma_f32_16x16x32_bf16(a[i], b[j], acc[i][j], 0, 0, 0);
    }

    // epilogue: C layout per frag: col = lane&15, row = (lane>>4)*4 + r
    #pragma unroll
    for (int i = 0; i < 4; ++i) {
        const int rl = wr * 64 + i * 16 + ((lane >> 4) << 2);
        const int grow = row0 + rl;
        #pragma unroll
        for (int j = 0; j < 4; ++j) {
            const int col = col0 + wc * 64 + j * 16 + (lane & 15);
            f32x4 v = acc[i][j];
            if (bias) {
                const float bv = bias[col];
                v[0] += bv; v[1] += bv; v[2] += bv; v[3] += bv;
            }
            if (relu) {
                v[0] = fmaxf(v[0], 0.f); v[1] = fmaxf(v[1], 0.f);
                v[2] = fmaxf(v[2], 0.f); v[3] = fmaxf(v[3], 0.f);
            }
            if (Cf) {
                float* C = Cf + (long long)bz * bsC;
                #pragma unroll
                for (int r = 0; r < 4; ++r) C[(size_t)(grow + r) * N + col] = v[r];
            }
            if (Ct) {  // bf16 transposed: [b=grow>>11][col][t=grow&2047], t block of 4
                ushort4 pk;
                pk.x = f2bf(v[0]); pk.y = f2bf(v[1]); pk.z = f2bf(v[2]); pk.w = f2bf(v[3]);
                *(ushort4*)(Ct + ((size_t)((grow >> 11) * 256 + col)) * 2048 + (grow & 2047)) = pk;
            }
        }
    }
}

// ---------------------------------------------------------------------------
// Fused LSTM step: gates = gather(h) @ WihP^T (+ hprev @ WhhP^T) + bias, then
// sigmoid/tanh pointwise, writing hnext (and cstate if not last step).
// Split-bf16 (hi/lo) on both operands, 3 MFMA terms -> ~fp32-grade gates.
// Weights pre-permuted: col n' = 4*h + gate, so a 128-col block owns all 4
// gates of 32 hidden units -> pointwise fused via LDS C-tile.
// ---------------------------------------------------------------------------
__global__ __launch_bounds__(256) void lstm_step_k(
    const float* __restrict__ h,        // d_out [64][2048][256] f32
    const float* __restrict__ hprev,    // [Nrows][256] f32 (null if j==0)
    float* __restrict__ hnext,          // [Nrows][256] f32
    float* __restrict__ cstate,         // [Nrows][256] f32
    const u16* __restrict__ WihH, const u16* __restrict__ WihL,
    const u16* __restrict__ WhhH, const u16* __restrict__ WhhL,
    const float* __restrict__ biasp,    // [1024] permuted (bih+bhh)
    int nw, int p, int j)
{
    __shared__ __align__(16) char smem[69632];   // 4*64*68*4 bytes
    u16 (*AsH)[32] = (u16(*)[32])smem;
    u16 (*AsL)[32] = (u16(*)[32])(smem + 8192);
    u16 (*BsH)[32] = (u16(*)[32])(smem + 16384);
    u16 (*BsL)[32] = (u16(*)[32])(smem + 24576);

    const int tid = threadIdx.x;
    const int wid = tid >> 6, lane = tid & 63;
    const int wr = wid >> 1, wc = wid & 1;
    const int row0 = blockIdx.x * 128, col0 = blockIdx.y * 128;
    const int first = (j == 0), last = (j == p - 1);

    // A gather pointers (x-part): seg s: n = row0 + s*32 + tid/8
    const float* rp[4];
    #pragma unroll
    for (int s = 0; s < 4; ++s) {
        const int n = row0 + s * 32 + (tid >> 3);
        const int b = n / nw, w = n - b * nw;
        rp[s] = h + ((size_t)b * T2 + (size_t)w * p + j) * H2 + ((tid & 7) << 2);
    }
    const float* hp = hprev ? (hprev + (size_t)(row0 + (tid >> 3)) * H2 + ((tid & 7) << 2))
                            : nullptr;
    const int arow = tid >> 3, acol = (tid & 7) << 2;

    const int sr = tid >> 2;
    const int skB = (tid & 3) << 3;
    const size_t wrow0 = (size_t)(col0 + sr) * H2 + skB;
    const size_t wrow1 = (size_t)(col0 + 64 + sr) * H2 + skB;
    char* ldsBH = smem + 16384;
    char* ldsBL = smem + 24576;
    const int wb = wid << 10;

    f32x4 acc[4][4];
    #pragma unroll
    for (int i = 0; i < 4; ++i)
        #pragma unroll
        for (int q = 0; q < 4; ++q) acc[i][q] = (f32x4){0.f, 0.f, 0.f, 0.f};

    const int KT = first ? 256 : 512;
    for (int k0 = 0; k0 < KT; k0 += 32) {
        __syncthreads();
        if (k0 < 256) {
            async16(WihH + wrow0 + k0, ldsBH + wb);
            async16(WihH + wrow1 + k0, ldsBH + 4096 + wb);
            async16(WihL + wrow0 + k0, ldsBL + wb);
            async16(WihL + wrow1 + k0, ldsBL + 4096 + wb);
            #pragma unroll
            for (int s = 0; s < 4; ++s) {
                const float4 v = *(const float4*)(rp[s] + k0);
                ushort4 hi4, lo4; split4(v, hi4, lo4);
                *(ushort4*)&AsH[s * 32 + arow][acol] = hi4;
                *(ushort4*)&AsL[s * 32 + arow][acol] = lo4;
            }
        } else {
            const int kk = k0 - 256;
            async16(WhhH + wrow0 + kk, ldsBH + wb);
            async16(WhhH + wrow1 + kk, ldsBH + 4096 + wb);
            async16(WhhL + wrow0 + kk, ldsBL + wb);
            async16(WhhL + wrow1 + kk, ldsBL + 4096 + wb);
            #pragma unroll
            for (int s = 0; s < 4; ++s) {
                const float4 v = *(const float4*)(hp + (size_t)(s * 32) * H2 + kk);
                ushort4 hi4, lo4; split4(v, hi4, lo4);
                *(ushort4*)&AsH[s * 32 + arow][acol] = hi4;
                *(ushort4*)&AsL[s * 32 + arow][acol] = lo4;
            }
        }
        __syncthreads();
        const int mb = lane & 15, kb = (lane >> 4) << 3;
        bf16x8 ah[4], al[4], bh[4], bl[4];
        #pragma unroll
        for (int i = 0; i < 4; ++i) {
            ah[i] = *(const bf16x8*)&AsH[wr * 64 + i * 16 + mb][kb];
            al[i] = *(const bf16x8*)&AsL[wr * 64 + i * 16 + mb][kb];
        }
        #pragma unroll
        for (int q = 0; q < 4; ++q) {
            bh[q] = *(const bf16x8*)&BsH[wc * 64 + q * 16 + mb][kb];
            bl[q] = *(const bf16x8*)&BsL[wc * 64 + q * 16 + mb][kb];
        }
        #pragma unroll
        for (int i = 0; i < 4; ++i)
            #pragma unroll
            for (int q = 0; q < 4; ++q) {
                acc[i][q] = __builtin_amdgcn_mfma_f32_16x16x32_bf16(ah[i], bh[q], acc[i][q], 0, 0, 0);
                acc[i][q] = __builtin_amdgcn_mfma_f32_16x16x32_bf16(al[i], bh[q], acc[i][q], 0, 0, 0);
                acc[i][q] = __builtin_amdgcn_mfma_f32_16x16x32_bf16(ah[i], bl[q], acc[i][q], 0, 0, 0);
            }
    }

    // stage gates (+bias) into per-wave LDS tile [64][68]
    __syncthreads();
    float* cw = (float*)smem + wid * (64 * 68);
    #pragma unroll
    for (int i = 0; i < 4; ++i) {
        const int rb2 = i * 16 + ((lane >> 4) << 2);
        #pragma unroll
        for (int q = 0; q < 4; ++q) {
            const int c = q * 16 + (lane & 15);
            const float bv = biasp[col0 + wc * 64 + c];
            #pragma unroll
            for (int r = 0; r < 4; ++r) cw[(rb2 + r) * 68 + c] = acc[i][q][r] + bv;
        }
    }
    __syncthreads();

    // fused pointwise: this block owns rows [row0+wr*64, +64), hidden units
    // hglob = col0/4 + wc*16 + (lane&15)
    const int hl = lane & 15;
    const int hglob = (col0 >> 2) + wc * 16 + hl;
    const int rb = lane >> 4;
    #pragma unroll
    for (int kk = 0; kk < 16; ++kk) {
        const int rl = rb + (kk << 2);
        const int n = row0 + wr * 64 + rl;
        const f32x4 g = *(const f32x4*)&cw[rl * 68 + (hl << 2)];
        const float si = 1.f / (1.f + __expf(-g[0]));
        const float sf = 1.f / (1.f + __expf(-g[1]));
        const float tg = tanh_f(g[2]);
        const float so = 1.f / (1.f + __expf(-g[3]));
        const float cp = first ? 0.f : cstate[(size_t)n * H2 + hglob];
        const float cn = sf * cp + si * tg;
        const float hv = so * tanh_f(cn);
        hnext[(size_t)n * H2 + hglob] = hv;
        if (!last) cstate[(size_t)n * H2 + hglob] = cn;
    }
}

// scatter window-end hidden states back into h (d_out)
__global__ __launch_bounds__(256) void scatter_h_k(
    const float* __restrict__ hs, float* __restrict__ out, int nw, int p, int Nrows)
{
    const int idx = blockIdx.x * 256 + threadIdx.x;
    if (idx >= Nrows * 64) return;
    const int n = idx >> 6, c4 = (idx & 63) << 2;
    const int b = n / nw, w = n - b * nw;
    *(float4*)(out + ((size_t)b * T2 + (size_t)w * p + (p - 1)) * H2 + c4) =
        *(const float4*)(hs + (size_t)n * H2 + c4);
}

// Wg transpose+cast: out[n][k] = bf16(in[k][n]), 256x256
__global__ __launch_bounds__(256) void convT_k(const float* __restrict__ in, u16* __restrict__ out)
{
    const int idx = blockIdx.x * 256 + threadIdx.x;
    const int r = idx >> 8, c = idx & 255;
    out[(size_t)c * 256 + r] = f2bf(in[idx]);
}

// LSTM weight permute+split: out[pass][4h+g][k] (hi,lo) from in[pass][g*256+h][k]
__global__ __launch_bounds__(256) void convW_k(
    const float* __restrict__ Wih, const float* __restrict__ Whh,
    u16* __restrict__ wih_hi, u16* __restrict__ wih_lo,
    u16* __restrict__ whh_hi, u16* __restrict__ whh_lo)
{
    const int idx = blockIdx.x * 256 + threadIdx.x;   // 4*1024*256 total
    const int pp = idx >> 18;
    const int np = (idx >> 8) & 1023;
    const int k = idx & 255;
    const int hh = np >> 2, g = np & 3;
    const size_t src = (size_t)pp * 262144 + (size_t)(g * 256 + hh) * 256 + k;
    float v = Wih[src];
    u16 hi = f2bf(v); u16 lo = f2bf(v - bf2f(hi));
    wih_hi[idx] = hi; wih_lo[idx] = lo;
    v = Whh[src];
    hi = f2bf(v); lo = f2bf(v - bf2f(hi));
    whh_hi[idx] = hi; whh_lo[idx] = lo;
}

__global__ __launch_bounds__(256) void convB_k(
    const float* __restrict__ bih, const float* __restrict__ bhh, float* __restrict__ bp)
{
    const int idx = blockIdx.x * 256 + threadIdx.x;   // 4096
    const int pp = idx >> 10, np = idx & 1023;
    const int hh = np >> 2, g = np & 3;
    bp[idx] = bih[pp * 1024 + g * 256 + hh] + bhh[pp * 1024 + g * 256 + hh];
}

// ---------------------------------------------------------------------------
extern "C" void kernel_launch(void* const* d_in, const int* in_sizes, int n_in,
                              void* d_out, int out_size, void* d_ws, size_t ws_size,
                              hipStream_t stream)
{
    const float* x   = (const float*)d_in[0];
    const float* adj = (const float*)d_in[1];
    const float* Wg0 = (const float*)d_in[2];
    const float* bg0 = (const float*)d_in[3];
    const float* Wg1 = (const float*)d_in[4];
    const float* bg1 = (const float*)d_in[5];
    const float* Wih = (const float*)d_in[6];
    const float* Whh = (const float*)d_in[7];
    const float* bih = (const float*)d_in[8];
    const float* bhh = (const float*)d_in[9];
    float* out = (float*)d_out;

    char* ws = (char*)d_ws;
    float* hs0 = (float*)ws;                        // 67,108,864 B
    float* hs1 = (float*)(ws + 67108864);           // 67,108,864 B (hs0+hs1 = p=1 buffer)
    float* cst = (float*)(ws + 134217728);          // 67,108,864 B
    char*  stR = ws + 201326592;                    // 67,108,864 B region
    u16* St = (u16*)stR;                            // GCN phase: support^T bf16
    u16* wih_hi = (u16*)stR;                        // LSTM phase (St dead): 2 MB each
    u16* wih_lo = (u16*)(stR + 2097152);
    u16* whh_hi = (u16*)(stR + 4194304);
    u16* whh_lo = (u16*)(stR + 6291456);
    float* bp   = (float*)(stR + 8388608);          // 16 KB
    u16* wg0t = (u16*)hs0;                          // GCN phase only (hs0 free)
    u16* wg1t = (u16*)(ws + 131072);

    // ---- GCN ----
    convT_k<<<256, 256, 0, stream>>>(Wg0, wg0t);
    convT_k<<<256, 256, 0, stream>>>(Wg1, wg1t);
    // support1^T = (x @ Wg0 + bg0)^T  (bf16, [b][h][t])
    gcn_gemm<<<dim3(1024, 2, 1), 256, 0, stream>>>(
        x, wg0t, bg0, nullptr, St, BT2, 256, 256, 0, 0, 0, 0);
    // h1 = relu(adj @ support1)  -> out (f32)
    gcn_gemm<<<dim3(16, 2, 64), 256, 0, stream>>>(
        adj, St, nullptr, out, nullptr, 2048, 256, 2048,
        0, (long long)256 * 2048, (long long)2048 * 256, 1);
    // support2^T = (h1 @ Wg1 + bg1)^T
    gcn_gemm<<<dim3(1024, 2, 1), 256, 0, stream>>>(
        out, wg1t, bg1, nullptr, St, BT2, 256, 256, 0, 0, 0, 0);
    // h2 = relu(adj @ support2)  -> out (f32)
    gcn_gemm<<<dim3(16, 2, 64), 256, 0, stream>>>(
        adj, St, nullptr, out, nullptr, 2048, 256, 2048,
        0, (long long)256 * 2048, (long long)2048 * 256, 1);

    // ---- LSTM weights (St region now dead) ----
    convW_k<<<4096, 256, 0, stream>>>(Wih, Whh, wih_hi, wih_lo, whh_hi, whh_lo);
    convB_k<<<16, 256, 0, stream>>>(bih, bhh, bp);

    // ---- skip-LSTM passes (in-place on out, deferred writes via hstate) ----
    for (int p = 1; p <= MAXP; ++p) {
        const int nw = T2 / p;
        const int Nrows = 64 * nw;
        const u16* WihH = wih_hi + (size_t)(p - 1) * 262144;
        const u16* WihL = wih_lo + (size_t)(p - 1) * 262144;
        const u16* WhhH = whh_hi + (size_t)(p - 1) * 262144;
        const u16* WhhL = whh_lo + (size_t)(p - 1) * 262144;
        const float* bpp = bp + (size_t)(p - 1) * 1024;
        for (int j = 0; j < p; ++j) {
            float* hn = (p == 1) ? hs0 : ((j & 1) ? hs1 : hs0);
            const float* hpv = (j == 0) ? nullptr : ((j & 1) ? hs0 : hs1);
            lstm_step_k<<<dim3(Nrows / 128, 8, 1), 256, 0, stream>>>(
                out, hpv, hn, cst, WihH, WihL, WhhH, WhhL, bpp, nw, p, j);
        }
        const float* hlast = (p == 1) ? hs0 : (((p - 1) & 1) ? hs1 : hs0);
        scatter_h_k<<<(Nrows * 64 + 255) / 256, 256, 0, stream>>>(hlast, out, nw, p, Nrows);
    }
}

// Round 3
// 1522.272 us; speedup vs baseline: 6.6442x; 1.7619x over previous
//
#include <hip/hip_runtime.h>
#include <hip/hip_bf16.h>

#define T2 2048
#define H2 256
#define BT2 131072          // B*T = 64*2048
#define MAXP 4

typedef __attribute__((ext_vector_type(8))) short bf16x8;
typedef __attribute__((ext_vector_type(4))) float f32x4;
typedef unsigned short u16;

__device__ __forceinline__ u16 f2bf(float f) {
    union { float f; unsigned u; } v; v.f = f;
    unsigned r = (v.u + 0x7FFFu + ((v.u >> 16) & 1u)) >> 16;
    return (u16)r;
}
__device__ __forceinline__ void async16(const void* g, void* l) {
    __builtin_amdgcn_global_load_lds((const __attribute__((address_space(1))) void*)g,
                                     (__attribute__((address_space(3))) void*)l, 16, 0, 0);
}
__device__ __forceinline__ float frcp(float x) { return __builtin_amdgcn_rcpf(x); }
__device__ __forceinline__ float sig_f(float x) { return frcp(1.f + __expf(-x)); }
__device__ __forceinline__ float tanh_f(float x) {
    return 1.f - 2.f * frcp(__expf(2.f * x) + 1.f);
}

// ---------------------------------------------------------------------------
// GCN GEMM (same structure as R2): C = op(A_f32 @ Bt_bf16^T + bias).
// Outputs: f32 row-major (Cf) and/or bf16 transposed St[b][col][t] (Ct)
// and/or bf16 row-major mirror Cx[b][t][col].
// ---------------------------------------------------------------------------
__global__ __launch_bounds__(256) void gcn_gemm(
    const float* __restrict__ A, const u16* __restrict__ Bt,
    const float* __restrict__ bias,
    float* __restrict__ Cf, u16* __restrict__ Ct, u16* __restrict__ Cx,
    int M, int N, int K,
    long long bsA, long long bsB, long long bsC, int relu)
{
    __shared__ __align__(16) u16 As[128][32];
    __shared__ __align__(16) u16 Bs[128][32];

    const int tid = threadIdx.x;
    const int wid = tid >> 6, lane = tid & 63;
    const int wr = wid >> 1, wc = wid & 1;
    const int row0 = blockIdx.x * 128, col0 = blockIdx.y * 128;
    const int bz = blockIdx.z;
    A  += (long long)bz * bsA;
    Bt += (long long)bz * bsB;

    const int sr = tid >> 2;
    const int skB = (tid & 3) << 3;
    const u16* Bg0 = Bt + (size_t)(col0 + sr) * K + skB;
    const u16* Bg1 = Bt + (size_t)(col0 + 64 + sr) * K + skB;
    char* ldsB = (char*)&Bs[0][0];
    const int wb = wid << 10;

    const float* Ag = A + (size_t)(row0 + (tid >> 3)) * K + ((tid & 7) << 2);
    const int arow = tid >> 3, acol = (tid & 7) << 2;

    f32x4 acc[4][4];
    #pragma unroll
    for (int i = 0; i < 4; ++i)
        #pragma unroll
        for (int j = 0; j < 4; ++j) acc[i][j] = (f32x4){0.f, 0.f, 0.f, 0.f};

    for (int k0 = 0; k0 < K; k0 += 32) {
        __syncthreads();
        async16(Bg0 + k0, ldsB + wb);
        async16(Bg1 + k0, ldsB + 4096 + wb);
        #pragma unroll
        for (int s = 0; s < 4; ++s) {
            const float4 v = *(const float4*)(Ag + (size_t)(s * 32) * K + k0);
            ushort4 h;
            h.x = f2bf(v.x); h.y = f2bf(v.y); h.z = f2bf(v.z); h.w = f2bf(v.w);
            *(ushort4*)&As[s * 32 + arow][acol] = h;
        }
        __syncthreads();
        const int mb = lane & 15, kb = (lane >> 4) << 3;
        bf16x8 a[4], b[4];
        #pragma unroll
        for (int i = 0; i < 4; ++i) a[i] = *(const bf16x8*)&As[wr * 64 + i * 16 + mb][kb];
        #pragma unroll
        for (int j = 0; j < 4; ++j) b[j] = *(const bf16x8*)&Bs[wc * 64 + j * 16 + mb][kb];
        #pragma unroll
        for (int i = 0; i < 4; ++i)
            #pragma unroll
            for (int j = 0; j < 4; ++j)
                acc[i][j] = __builtin_amdgcn_mfma_f32_16x16x32_bf16(a[i], b[j], acc[i][j], 0, 0, 0);
    }

    #pragma unroll
    for (int i = 0; i < 4; ++i) {
        const int rl = wr * 64 + i * 16 + ((lane >> 4) << 2);
        const int grow = row0 + rl;
        #pragma unroll
        for (int j = 0; j < 4; ++j) {
            const int col = col0 + wc * 64 + j * 16 + (lane & 15);
            f32x4 v = acc[i][j];
            if (bias) {
                const float bv = bias[col];
                v[0] += bv; v[1] += bv; v[2] += bv; v[3] += bv;
            }
            if (relu) {
                v[0] = fmaxf(v[0], 0.f); v[1] = fmaxf(v[1], 0.f);
                v[2] = fmaxf(v[2], 0.f); v[3] = fmaxf(v[3], 0.f);
            }
            if (Cf) {
                float* C = Cf + (long long)bz * bsC;
                #pragma unroll
                for (int r = 0; r < 4; ++r) C[(size_t)(grow + r) * N + col] = v[r];
            }
            if (Ct) {  // bf16 transposed: [b][col][t], t block of 4
                ushort4 pk;
                pk.x = f2bf(v[0]); pk.y = f2bf(v[1]); pk.z = f2bf(v[2]); pk.w = f2bf(v[3]);
                *(ushort4*)(Ct + ((size_t)((grow >> 11) * 256 + col)) * 2048 + (grow & 2047)) = pk;
            }
            if (Cx) {  // bf16 row-major mirror [b][t][col]; grow already = b*2048+t? no: M=2048, bz=b
                #pragma unroll
                for (int r = 0; r < 4; ++r)
                    Cx[((size_t)bz * 2048 + grow + r) * 256 + col] = f2bf(v[r]);
            }
        }
    }
}

// ---------------------------------------------------------------------------
// LSTM step, 1-term bf16 MFMA, gate-major weights, in-register pointwise.
// A (x-part): gathered from bf16 mirror Ax via per-lane global_load_lds.
// A (recurrent, k>=256): hprev bf16 [Nrows][256].
// Weights wP [1024][256] bf16, col-permuted n' = (h>>4)*64 + g*16 + (h&15).
// Epilogue: frag q = gate q; writes hnext bf16 (+ cst f32 non-last,
// + out f32 last).
// ---------------------------------------------------------------------------
__global__ __launch_bounds__(256) void lstm_step_k(
    const u16* __restrict__ Ax, const u16* __restrict__ hprev,
    u16* __restrict__ hnext, float* __restrict__ outF, float* __restrict__ cst,
    const u16* __restrict__ wih, const u16* __restrict__ whh,
    const float* __restrict__ biasp, int nw, int p, int j)
{
    __shared__ __align__(16) u16 As[128][32];
    __shared__ __align__(16) u16 Bs[128][32];

    const int tid = threadIdx.x;
    const int wid = tid >> 6, lane = tid & 63;
    const int wr = wid >> 1, wc = wid & 1;
    const int row0 = blockIdx.x * 128, col0 = blockIdx.y * 128;
    const int first = (j == 0), last = (j == p - 1);

    // staging: lane covers LDS row sr (and sr+64), k-chunk slot (tid&3).
    // XOR swizzle: LDS[r][slot s] holds global k-chunk s ^ (r&3).
    const int sr = tid >> 2;
    const int slot = tid & 3;
    const int skA = ((slot ^ (sr & 3)) << 3);     // swizzled global k-offset (elems)
    // x-gather source rows
    const int n0 = row0 + sr, n1 = n0 + 64;
    const unsigned unw = (unsigned)nw;
    const int b0g = (unsigned)n0 / unw, w0g = n0 - b0g * nw;
    const int b1g = (unsigned)n1 / unw, w1g = n1 - b1g * nw;
    const u16* ax0 = Ax + ((size_t)b0g * T2 + (size_t)w0g * p + j) * H2 + skA;
    const u16* ax1 = Ax + ((size_t)b1g * T2 + (size_t)w1g * p + j) * H2 + skA;
    const u16* hp0 = hprev ? hprev + (size_t)n0 * H2 + skA : nullptr;
    const u16* hp1 = hprev ? hprev + (size_t)n1 * H2 + skA : nullptr;
    const size_t wrow0 = (size_t)(col0 + sr) * H2 + skA;
    const size_t wrow1 = (size_t)(col0 + 64 + sr) * H2 + skA;

    char* ldsA = (char*)&As[0][0];
    char* ldsB = (char*)&Bs[0][0];
    const int wb = wid << 10;

    f32x4 acc[4][4];
    #pragma unroll
    for (int i = 0; i < 4; ++i)
        #pragma unroll
        for (int q = 0; q < 4; ++q) acc[i][q] = (f32x4){0.f, 0.f, 0.f, 0.f};

    const int KT = first ? 256 : 512;
    for (int k0 = 0; k0 < KT; k0 += 32) {
        __syncthreads();
        if (k0 < 256) {
            async16(ax0 + k0, ldsA + wb);
            async16(ax1 + k0, ldsA + 4096 + wb);
            async16(wih + wrow0 + k0, ldsB + wb);
            async16(wih + wrow1 + k0, ldsB + 4096 + wb);
        } else {
            const int kk = k0 - 256;
            async16(hp0 + kk, ldsA + wb);
            async16(hp1 + kk, ldsA + 4096 + wb);
            async16(whh + wrow0 + kk, ldsB + wb);
            async16(whh + wrow1 + kk, ldsB + 4096 + wb);
        }
        __syncthreads();
        const int mb = lane & 15;
        const int cbyte = (lane >> 4) << 4;        // 0,16,32,48 bytes (8 elems)
        bf16x8 a[4], b[4];
        #pragma unroll
        for (int i = 0; i < 4; ++i) {
            const int r = wr * 64 + i * 16 + mb;
            a[i] = *(const bf16x8*)(ldsA + r * 64 + (cbyte ^ ((r & 3) << 4)));
        }
        #pragma unroll
        for (int q = 0; q < 4; ++q) {
            const int r = wc * 64 + q * 16 + mb;
            b[q] = *(const bf16x8*)(ldsB + r * 64 + (cbyte ^ ((r & 3) << 4)));
        }
        #pragma unroll
        for (int i = 0; i < 4; ++i)
            #pragma unroll
            for (int q = 0; q < 4; ++q)
                acc[i][q] = __builtin_amdgcn_mfma_f32_16x16x32_bf16(a[i], b[q], acc[i][q], 0, 0, 0);
    }

    // in-register pointwise epilogue: frag q = gate q (i,f,g,o)
    const int u = lane & 15;
    const int colb = col0 + wc * 64;
    const int hu = (colb >> 2) + u;                // global hidden unit
    float bq[4];
    #pragma unroll
    for (int q = 0; q < 4; ++q) bq[q] = biasp[colb + q * 16 + u];

    #pragma unroll
    for (int i = 0; i < 4; ++i) {
        const int rbase = row0 + wr * 64 + i * 16 + ((lane >> 4) << 2);
        #pragma unroll
        for (int r = 0; r < 4; ++r) {
            const int n = rbase + r;
            const float gi = acc[i][0][r] + bq[0];
            const float gf = acc[i][1][r] + bq[1];
            const float gg = acc[i][2][r] + bq[2];
            const float go = acc[i][3][r] + bq[3];
            const float si = sig_f(gi), sf = sig_f(gf), so = sig_f(go);
            const float tg = tanh_f(gg);
            const float cp = first ? 0.f : cst[(size_t)n * H2 + hu];
            const float cn = sf * cp + si * tg;
            const float hv = so * tanh_f(cn);
            hnext[(size_t)n * H2 + hu] = f2bf(hv);
            if (last) {
                const unsigned b = (unsigned)n / unw;
                const int w = n - (int)b * nw;
                outF[((size_t)b * T2 + (size_t)w * p + (p - 1)) * H2 + hu] = hv;
            } else {
                cst[(size_t)n * H2 + hu] = cn;
            }
        }
    }
}

// update mirror Ax at window-end positions from deferred hnext (bf16 copy)
__global__ __launch_bounds__(256) void scatter_ax_k(
    const u16* __restrict__ hs, u16* __restrict__ Ax, int nw, int p, int Nrows)
{
    const int idx = blockIdx.x * 256 + threadIdx.x;   // 16B per thread
    if (idx >= Nrows * 32) return;
    const int n = idx >> 5, c8 = (idx & 31) << 3;
    const unsigned b = (unsigned)n / (unsigned)nw;
    const int w = n - (int)b * nw;
    *(uint4*)(Ax + ((size_t)b * T2 + (size_t)w * p + (p - 1)) * H2 + c8) =
        *(const uint4*)(hs + (size_t)n * H2 + c8);
}

// Wg transpose+cast: out[n][k] = bf16(in[k][n]), 256x256
__global__ __launch_bounds__(256) void convT_k(const float* __restrict__ in, u16* __restrict__ out)
{
    const int idx = blockIdx.x * 256 + threadIdx.x;
    const int r = idx >> 8, c = idx & 255;
    out[(size_t)c * 256 + r] = f2bf(in[idx]);
}

// LSTM weight gate-major permute: wP[pass][n'][k], n' = (h>>4)*64+g*16+(h&15)
__global__ __launch_bounds__(256) void convW_k(
    const float* __restrict__ Wih, const float* __restrict__ Whh,
    u16* __restrict__ wih_p, u16* __restrict__ whh_p)
{
    const int idx = blockIdx.x * 256 + threadIdx.x;   // 4*1024*256 total
    const int pp = idx >> 18;
    const int np = (idx >> 8) & 1023;
    const int k = idx & 255;
    const int group = np >> 6, g = (np >> 4) & 3, uu = np & 15;
    const int hh = group * 16 + uu;
    const size_t src = (size_t)pp * 262144 + (size_t)(g * 256 + hh) * 256 + k;
    wih_p[idx] = f2bf(Wih[src]);
    whh_p[idx] = f2bf(Whh[src]);
}

__global__ __launch_bounds__(256) void convB_k(
    const float* __restrict__ bih, const float* __restrict__ bhh, float* __restrict__ bp)
{
    const int idx = blockIdx.x * 256 + threadIdx.x;   // 4096
    const int pp = idx >> 10, np = idx & 1023;
    const int group = np >> 6, g = (np >> 4) & 3, uu = np & 15;
    const int hh = group * 16 + uu;
    bp[idx] = bih[pp * 1024 + g * 256 + hh] + bhh[pp * 1024 + g * 256 + hh];
}

// ---------------------------------------------------------------------------
extern "C" void kernel_launch(void* const* d_in, const int* in_sizes, int n_in,
                              void* d_out, int out_size, void* d_ws, size_t ws_size,
                              hipStream_t stream)
{
    const float* x   = (const float*)d_in[0];
    const float* adj = (const float*)d_in[1];
    const float* Wg0 = (const float*)d_in[2];
    const float* bg0 = (const float*)d_in[3];
    const float* Wg1 = (const float*)d_in[4];
    const float* bg1 = (const float*)d_in[5];
    const float* Wih = (const float*)d_in[6];
    const float* Whh = (const float*)d_in[7];
    const float* bih = (const float*)d_in[8];
    const float* bhh = (const float*)d_in[9];
    float* out = (float*)d_out;

    char* ws = (char*)d_ws;
    u16*   Ax  = (u16*)ws;                          // 67,108,864 B  bf16 mirror of h
    u16*   hsB = (u16*)(ws + 67108864);             // 67,108,864 B  hs0 | hs1 (33.5 MB each)
    u16*   hs0 = hsB;
    u16*   hs1 = (u16*)(ws + 67108864 + 33554432);
    float* cst = (float*)(ws + 134217728);          // 67,108,864 B  f32 cell state
    u16*   wihP = (u16*)(ws + 201326592);           // 2,097,152 B
    u16*   whhP = (u16*)(ws + 203423744);           // 2,097,152 B
    float* bp   = (float*)(ws + 205520896);         // 16,384 B
    u16*   wg0t = (u16*)(ws + 205537280);           // 131,072 B
    u16*   wg1t = (u16*)(ws + 205668352);           // 131,072 B
    u16*   St   = hsB;                              // GCN phase only (67.1 MB)

    // ---- GCN ----
    convT_k<<<256, 256, 0, stream>>>(Wg0, wg0t);
    convT_k<<<256, 256, 0, stream>>>(Wg1, wg1t);
    // support1^T = (x @ Wg0 + bg0)^T  (bf16 [b][h][t])
    gcn_gemm<<<dim3(1024, 2, 1), 256, 0, stream>>>(
        x, wg0t, bg0, nullptr, St, nullptr, BT2, 256, 256, 0, 0, 0, 0);
    // h1 = relu(adj @ support1) -> out (f32)
    gcn_gemm<<<dim3(16, 2, 64), 256, 0, stream>>>(
        adj, St, nullptr, out, nullptr, nullptr, 2048, 256, 2048,
        0, (long long)256 * 2048, (long long)2048 * 256, 1);
    // support2^T = (h1 @ Wg1 + bg1)^T
    gcn_gemm<<<dim3(1024, 2, 1), 256, 0, stream>>>(
        out, wg1t, bg1, nullptr, St, nullptr, BT2, 256, 256, 0, 0, 0, 0);
    // h2 = relu(adj @ support2) -> Ax mirror only (out gets fully overwritten by p=1)
    gcn_gemm<<<dim3(16, 2, 64), 256, 0, stream>>>(
        adj, St, nullptr, nullptr, nullptr, Ax, 2048, 256, 2048,
        0, (long long)256 * 2048, 0, 1);

    // ---- LSTM weights (St region reused as hs after this) ----
    convW_k<<<4096, 256, 0, stream>>>(Wih, Whh, wihP, whhP);
    convB_k<<<16, 256, 0, stream>>>(bih, bhh, bp);

    // ---- skip-LSTM passes ----
    for (int p = 1; p <= MAXP; ++p) {
        const int nw = T2 / p;
        const int Nrows = 64 * nw;                  // 131072 / 65536 / 43648 / 32768
        const u16* wihp = wihP + (size_t)(p - 1) * 262144;
        const u16* whhp = whhP + (size_t)(p - 1) * 262144;
        const float* bpp = bp + (size_t)(p - 1) * 1024;
        for (int j = 0; j < p; ++j) {
            u16* hn = (p == 1) ? hsB : ((j & 1) ? hs1 : hs0);
            const u16* hpv = (j == 0) ? nullptr : ((j & 1) ? hs0 : hs1);
            lstm_step_k<<<dim3(Nrows / 128, 8, 1), 256, 0, stream>>>(
                Ax, hpv, hn, out, cst, wihp, whhp, bpp, nw, p, j);
        }
        const u16* hlast = (p == 1) ? hsB : (((p - 1) & 1) ? hs1 : hs0);
        scatter_ax_k<<<(Nrows * 32 + 255) / 256, 256, 0, stream>>>(hlast, Ax, nw, p, Nrows);
    }
}

// Round 4
// 1381.823 us; speedup vs baseline: 7.3196x; 1.1016x over previous
//
#include <hip/hip_runtime.h>
#include <hip/hip_bf16.h>

#define T2 2048
#define H2 256
#define BT2 131072          // B*T = 64*2048
#define MAXP 4

typedef __attribute__((ext_vector_type(8))) short bf16x8;
typedef __attribute__((ext_vector_type(4))) float f32x4;
typedef unsigned short u16;

__device__ __forceinline__ u16 f2bf(float f) {
    union { float f; unsigned u; } v; v.f = f;
    unsigned r = (v.u + 0x7FFFu + ((v.u >> 16) & 1u)) >> 16;
    return (u16)r;
}
__device__ __forceinline__ void async16(const void* g, void* l) {
    __builtin_amdgcn_global_load_lds((const __attribute__((address_space(1))) void*)g,
                                     (__attribute__((address_space(3))) void*)l, 16, 0, 0);
}
__device__ __forceinline__ float frcp(float x) { return __builtin_amdgcn_rcpf(x); }
__device__ __forceinline__ float sig_f(float x) { return frcp(1.f + __expf(-x)); }
__device__ __forceinline__ float tanh_f(float x) {
    return 1.f - 2.f * frcp(__expf(2.f * x) + 1.f);
}

// f32 -> bf16 cast, 4 elems/thread
__global__ __launch_bounds__(256) void cast_bf16_k(
    const float* __restrict__ in, u16* __restrict__ out, int n4)
{
    const int i = blockIdx.x * 256 + threadIdx.x;
    if (i >= n4) return;
    const float4 v = ((const float4*)in)[i];
    ushort4 h;
    h.x = f2bf(v.x); h.y = f2bf(v.y); h.z = f2bf(v.z); h.w = f2bf(v.w);
    ((ushort4*)out)[i] = h;
}

// ---------------------------------------------------------------------------
// Pure-bf16 GEMM: C = op(A @ Bt^T + bias). A [M][K] bf16 row-major,
// Bt [N=256][K] bf16 (batch-strided by bsB). 128x128 tile, BK=64, 4 waves,
// 8-slot XOR-swizzled LDS (pre-swizzled global source, linear LDS dest).
// mode 0: plain decode (bx=bid>>1, by=bid&1, bz=0)      [support GEMMs]
// mode 1: XCD-chunked, xy-major/z-minor                  [adj GEMMs, nwg=2048]
// Outputs: Ct bf16 transposed [b][col][t] (b=grow>>11), Cx bf16 mirror
// [bz][t=grow][col].
// ---------------------------------------------------------------------------
__global__ __launch_bounds__(256) void bgemm_k(
    const u16* __restrict__ A, const u16* __restrict__ Bt,
    const float* __restrict__ bias,
    u16* __restrict__ Ct, u16* __restrict__ Cx,
    int K, long long bsB, int relu, int mode)
{
    __shared__ __align__(16) u16 As[128][64];
    __shared__ __align__(16) u16 Bs[128][64];

    const int tid = threadIdx.x;
    const int wid = tid >> 6, lane = tid & 63;
    const int wr = wid >> 1, wc = wid & 1;

    int bx, by, bz;
    if (mode == 0) { bx = blockIdx.x >> 1; by = blockIdx.x & 1; bz = 0; }
    else {
        const int l = ((blockIdx.x & 7) << 8) + (blockIdx.x >> 3);
        bz = l & 63;
        const int xy = l >> 6;
        bx = xy >> 1; by = xy & 1;
    }
    const int row0 = bx * 128, col0 = by * 128;
    const u16* Bp = Bt + (long long)bz * bsB;

    // staging: thread covers rows srow+32s, physical slot tid&7 holds global
    // k-chunk (tid&7)^(srow&7)  (8-bank spread on frag reads)
    const int srow = tid >> 3;                   // 0..31
    const int skA = ((tid ^ srow) & 7) << 3;     // swizzled k-elem offset
    const u16* Ag = A + (size_t)(row0 + srow) * K + skA;
    const u16* Bg = Bp + (size_t)(col0 + srow) * K + skA;
    char* ldsA = (char*)&As[0][0];
    char* ldsB = (char*)&Bs[0][0];
    const int wb = wid << 10;

    f32x4 acc[4][4];
    #pragma unroll
    for (int i = 0; i < 4; ++i)
        #pragma unroll
        for (int q = 0; q < 4; ++q) acc[i][q] = (f32x4){0.f, 0.f, 0.f, 0.f};

    for (int k0 = 0; k0 < K; k0 += 64) {
        __syncthreads();
        #pragma unroll
        for (int s = 0; s < 4; ++s) {
            async16(Ag + (size_t)(s * 32) * K + k0, ldsA + s * 4096 + wb);
            async16(Bg + (size_t)(s * 32) * K + k0, ldsB + s * 4096 + wb);
        }
        __syncthreads();
        const int mb = lane & 15, g = lane >> 4;
        #pragma unroll
        for (int kk = 0; kk < 2; ++kk) {
            bf16x8 a[4], b[4];
            #pragma unroll
            for (int i = 0; i < 4; ++i) {
                const int r = wr * 64 + i * 16 + mb;
                a[i] = *(const bf16x8*)(ldsA + r * 128 + ((((kk << 2) + g) ^ (r & 7)) << 4));
            }
            #pragma unroll
            for (int q = 0; q < 4; ++q) {
                const int r = wc * 64 + q * 16 + mb;
                b[q] = *(const bf16x8*)(ldsB + r * 128 + ((((kk << 2) + g) ^ (r & 7)) << 4));
            }
            #pragma unroll
            for (int i = 0; i < 4; ++i)
                #pragma unroll
                for (int q = 0; q < 4; ++q)
                    acc[i][q] = __builtin_amdgcn_mfma_f32_16x16x32_bf16(a[i], b[q], acc[i][q], 0, 0, 0);
        }
    }

    #pragma unroll
    for (int i = 0; i < 4; ++i) {
        const int rl = wr * 64 + i * 16 + ((lane >> 4) << 2);
        const int grow = row0 + rl;
        #pragma unroll
        for (int q = 0; q < 4; ++q) {
            const int col = col0 + wc * 64 + q * 16 + (lane & 15);
            f32x4 v = acc[i][q];
            if (bias) {
                const float bv = bias[col];
                v[0] += bv; v[1] += bv; v[2] += bv; v[3] += bv;
            }
            if (relu) {
                v[0] = fmaxf(v[0], 0.f); v[1] = fmaxf(v[1], 0.f);
                v[2] = fmaxf(v[2], 0.f); v[3] = fmaxf(v[3], 0.f);
            }
            if (Ct) {  // bf16 transposed [b][col][t], t-block of 4
                ushort4 pk;
                pk.x = f2bf(v[0]); pk.y = f2bf(v[1]); pk.z = f2bf(v[2]); pk.w = f2bf(v[3]);
                *(ushort4*)(Ct + ((size_t)((grow >> 11) * 256 + col)) * 2048 + (grow & 2047)) = pk;
            }
            if (Cx) {  // bf16 mirror [bz][t][col]
                #pragma unroll
                for (int r = 0; r < 4; ++r)
                    Cx[((size_t)bz * 2048 + grow + r) * 256 + col] = f2bf(v[r]);
            }
        }
    }
}

// ---------------------------------------------------------------------------
// LSTM step: gates = gather(Ax) @ wih^T (+ hprev @ whh^T) + bias, fused
// pointwise. BK=64, 8-slot swizzle, XCD-chunked grid (8 consecutive logical
// blocks share the A-tile -> L2 hits). Gate-major weights: frag q = gate q.
// ---------------------------------------------------------------------------
__global__ __launch_bounds__(256) void lstm_step_k(
    const u16* __restrict__ Ax, const u16* __restrict__ hprev,
    u16* __restrict__ hnext, float* __restrict__ outF, float* __restrict__ cst,
    const u16* __restrict__ wih, const u16* __restrict__ whh,
    const float* __restrict__ biasp, int nw, int p, int j, int cpx)
{
    __shared__ __align__(16) u16 As[128][64];
    __shared__ __align__(16) u16 Bs[128][64];

    const int tid = threadIdx.x;
    const int wid = tid >> 6, lane = tid & 63;
    const int wr = wid >> 1, wc = wid & 1;

    const int l = (blockIdx.x & 7) * cpx + (blockIdx.x >> 3);  // logical = x*8+y
    const int col0 = (l & 7) << 7;
    const int row0 = (l >> 3) << 7;
    const int first = (j == 0), last = (j == p - 1);

    const int srow = tid >> 3;
    const int skA = ((tid ^ srow) & 7) << 3;
    const unsigned unw = (unsigned)nw;

    const u16* axp[4];
    const u16* hpp[4];
    size_t wrow[4];
    #pragma unroll
    for (int s = 0; s < 4; ++s) {
        const int r = srow + 32 * s;
        const int n = row0 + r;
        const unsigned b = (unsigned)n / unw;
        const int w = n - (int)b * nw;
        axp[s] = Ax + ((size_t)b * T2 + (size_t)w * p + j) * H2 + skA;
        hpp[s] = hprev ? hprev + (size_t)n * H2 + skA : nullptr;
        wrow[s] = (size_t)(col0 + r) * H2 + skA;
    }
    char* ldsA = (char*)&As[0][0];
    char* ldsB = (char*)&Bs[0][0];
    const int wb = wid << 10;

    f32x4 acc[4][4];
    #pragma unroll
    for (int i = 0; i < 4; ++i)
        #pragma unroll
        for (int q = 0; q < 4; ++q) acc[i][q] = (f32x4){0.f, 0.f, 0.f, 0.f};

    const int KT = first ? 256 : 512;
    for (int k0 = 0; k0 < KT; k0 += 64) {
        __syncthreads();
        if (k0 < 256) {
            #pragma unroll
            for (int s = 0; s < 4; ++s) {
                async16(axp[s] + k0, ldsA + s * 4096 + wb);
                async16(wih + wrow[s] + k0, ldsB + s * 4096 + wb);
            }
        } else {
            const int kk = k0 - 256;
            #pragma unroll
            for (int s = 0; s < 4; ++s) {
                async16(hpp[s] + kk, ldsA + s * 4096 + wb);
                async16(whh + wrow[s] + kk, ldsB + s * 4096 + wb);
            }
        }
        __syncthreads();
        const int mb = lane & 15, g = lane >> 4;
        #pragma unroll
        for (int kk = 0; kk < 2; ++kk) {
            bf16x8 a[4], b[4];
            #pragma unroll
            for (int i = 0; i < 4; ++i) {
                const int r = wr * 64 + i * 16 + mb;
                a[i] = *(const bf16x8*)(ldsA + r * 128 + ((((kk << 2) + g) ^ (r & 7)) << 4));
            }
            #pragma unroll
            for (int q = 0; q < 4; ++q) {
                const int r = wc * 64 + q * 16 + mb;
                b[q] = *(const bf16x8*)(ldsB + r * 128 + ((((kk << 2) + g) ^ (r & 7)) << 4));
            }
            #pragma unroll
            for (int i = 0; i < 4; ++i)
                #pragma unroll
                for (int q = 0; q < 4; ++q)
                    acc[i][q] = __builtin_amdgcn_mfma_f32_16x16x32_bf16(a[i], b[q], acc[i][q], 0, 0, 0);
        }
    }

    // in-register pointwise epilogue: frag q = gate q (i,f,g,o)
    const int u = lane & 15;
    const int colb = col0 + wc * 64;
    const int hu = (colb >> 2) + u;
    float bq[4];
    #pragma unroll
    for (int q = 0; q < 4; ++q) bq[q] = biasp[colb + q * 16 + u];

    #pragma unroll
    for (int i = 0; i < 4; ++i) {
        const int rbase = row0 + wr * 64 + i * 16 + ((lane >> 4) << 2);
        #pragma unroll
        for (int r = 0; r < 4; ++r) {
            const int n = rbase + r;
            const float gi = acc[i][0][r] + bq[0];
            const float gf = acc[i][1][r] + bq[1];
            const float gg = acc[i][2][r] + bq[2];
            const float go = acc[i][3][r] + bq[3];
            const float si = sig_f(gi), sf = sig_f(gf), so = sig_f(go);
            const float tg = tanh_f(gg);
            const float cp = first ? 0.f : cst[(size_t)n * H2 + hu];
            const float cn = sf * cp + si * tg;
            const float hv = so * tanh_f(cn);
            hnext[(size_t)n * H2 + hu] = f2bf(hv);
            if (last) {
                const unsigned b = (unsigned)n / unw;
                const int w = n - (int)b * nw;
                outF[((size_t)b * T2 + (size_t)w * p + (p - 1)) * H2 + hu] = hv;
            } else {
                cst[(size_t)n * H2 + hu] = cn;
            }
        }
    }
}

// update mirror Ax at window-end positions from deferred hnext (bf16 copy)
__global__ __launch_bounds__(256) void scatter_ax_k(
    const u16* __restrict__ hs, u16* __restrict__ Ax, int nw, int p, int Nrows)
{
    const int idx = blockIdx.x * 256 + threadIdx.x;   // 16B per thread
    if (idx >= Nrows * 32) return;
    const int n = idx >> 5, c8 = (idx & 31) << 3;
    const unsigned b = (unsigned)n / (unsigned)nw;
    const int w = n - (int)b * nw;
    *(uint4*)(Ax + ((size_t)b * T2 + (size_t)w * p + (p - 1)) * H2 + c8) =
        *(const uint4*)(hs + (size_t)n * H2 + c8);
}

// Wg transpose+cast: out[n][k] = bf16(in[k][n]), 256x256
__global__ __launch_bounds__(256) void convT_k(const float* __restrict__ in, u16* __restrict__ out)
{
    const int idx = blockIdx.x * 256 + threadIdx.x;
    const int r = idx >> 8, c = idx & 255;
    out[(size_t)c * 256 + r] = f2bf(in[idx]);
}

// LSTM weight gate-major permute: wP[pass][n'][k], n' = (h>>4)*64+g*16+(h&15)
__global__ __launch_bounds__(256) void convW_k(
    const float* __restrict__ Wih, const float* __restrict__ Whh,
    u16* __restrict__ wih_p, u16* __restrict__ whh_p)
{
    const int idx = blockIdx.x * 256 + threadIdx.x;   // 4*1024*256 total
    const int pp = idx >> 18;
    const int np = (idx >> 8) & 1023;
    const int k = idx & 255;
    const int group = np >> 6, g = (np >> 4) & 3, uu = np & 15;
    const int hh = group * 16 + uu;
    const size_t src = (size_t)pp * 262144 + (size_t)(g * 256 + hh) * 256 + k;
    wih_p[idx] = f2bf(Wih[src]);
    whh_p[idx] = f2bf(Whh[src]);
}

__global__ __launch_bounds__(256) void convB_k(
    const float* __restrict__ bih, const float* __restrict__ bhh, float* __restrict__ bp)
{
    const int idx = blockIdx.x * 256 + threadIdx.x;   // 4096
    const int pp = idx >> 10, np = idx & 1023;
    const int group = np >> 6, g = (np >> 4) & 3, uu = np & 15;
    const int hh = group * 16 + uu;
    bp[idx] = bih[pp * 1024 + g * 256 + hh] + bhh[pp * 1024 + g * 256 + hh];
}

// ---------------------------------------------------------------------------
extern "C" void kernel_launch(void* const* d_in, const int* in_sizes, int n_in,
                              void* d_out, int out_size, void* d_ws, size_t ws_size,
                              hipStream_t stream)
{
    const float* x   = (const float*)d_in[0];
    const float* adj = (const float*)d_in[1];
    const float* Wg0 = (const float*)d_in[2];
    const float* bg0 = (const float*)d_in[3];
    const float* Wg1 = (const float*)d_in[4];
    const float* bg1 = (const float*)d_in[5];
    const float* Wih = (const float*)d_in[6];
    const float* Whh = (const float*)d_in[7];
    const float* bih = (const float*)d_in[8];
    const float* bhh = (const float*)d_in[9];
    float* out = (float*)d_out;

    char* ws = (char*)d_ws;
    u16*   Ax   = (u16*)ws;                         // 67,108,864 B  bf16 mirror (h1x then h2)
    u16*   hsB  = (u16*)(ws + 67108864);            // 67,108,864 B  St (GCN) / hs0|hs1 (LSTM)
    u16*   hs0  = hsB;
    u16*   hs1  = (u16*)(ws + 67108864 + 33554432);
    float* cst  = (float*)(ws + 134217728);         // 67,108,864 B  f32 cell state
    u16*   xbf  = (u16*)(ws + 134217728);           // alias: x bf16 (dead before LSTM)
    char*  wreg = ws + 201326592;                   // 8,388,608 B region
    u16*   adjbf = (u16*)wreg;                      // GCN phase
    u16*   wihP  = (u16*)wreg;                      // LSTM phase (adjbf dead)
    u16*   whhP  = (u16*)(wreg + 2097152);
    float* bp    = (float*)(wreg + 4194304);
    u16*   wg0t  = (u16*)(ws + 209715200);          // 131,072 B
    u16*   wg1t  = (u16*)(ws + 209846272);          // 131,072 B
    u16*   St    = hsB;

    // ---- casts / weight prep ----
    cast_bf16_k<<<32768, 256, 0, stream>>>(x, xbf, 8388608);     // 33.5M elems
    cast_bf16_k<<<4096, 256, 0, stream>>>(adj, adjbf, 1048576);  // 4.2M elems
    convT_k<<<256, 256, 0, stream>>>(Wg0, wg0t);
    convT_k<<<256, 256, 0, stream>>>(Wg1, wg1t);

    // ---- GCN ----
    // support1^T = (x @ Wg0 + bg0)^T -> St
    bgemm_k<<<2048, 256, 0, stream>>>(xbf, wg0t, bg0, St, nullptr, 256, 0, 0, 0);
    // h1 = relu(adj @ support1) -> Ax mirror (bf16)
    bgemm_k<<<2048, 256, 0, stream>>>(adjbf, St, nullptr, nullptr, Ax, 2048,
                                      (long long)256 * 2048, 1, 1);
    // support2^T = (h1 @ Wg1 + bg1)^T -> St
    bgemm_k<<<2048, 256, 0, stream>>>(Ax, wg1t, bg1, St, nullptr, 256, 0, 0, 0);
    // h2 = relu(adj @ support2) -> Ax mirror (out fully overwritten by p=1 pass)
    bgemm_k<<<2048, 256, 0, stream>>>(adjbf, St, nullptr, nullptr, Ax, 2048,
                                      (long long)256 * 2048, 1, 1);

    // ---- LSTM weights (adjbf region now dead) ----
    convW_k<<<4096, 256, 0, stream>>>(Wih, Whh, wihP, whhP);
    convB_k<<<16, 256, 0, stream>>>(bih, bhh, bp);

    // ---- skip-LSTM passes ----
    for (int p = 1; p <= MAXP; ++p) {
        const int nw = T2 / p;
        const int Nrows = 64 * nw;                  // 131072 / 65536 / 43648 / 32768
        const int cpx = Nrows / 128;                // logical x-tiles; nwg = cpx*8
        const u16* wihp = wihP + (size_t)(p - 1) * 262144;
        const u16* whhp = whhP + (size_t)(p - 1) * 262144;
        const float* bpp = bp + (size_t)(p - 1) * 1024;
        for (int j = 0; j < p; ++j) {
            u16* hn = (p == 1) ? hsB : ((j & 1) ? hs1 : hs0);
            const u16* hpv = (j == 0) ? nullptr : ((j & 1) ? hs0 : hs1);
            lstm_step_k<<<cpx * 8, 256, 0, stream>>>(
                Ax, hpv, hn, out, cst, wihp, whhp, bpp, nw, p, j, cpx);
        }
        const u16* hlast = (p == 1) ? hsB : (((p - 1) & 1) ? hs1 : hs0);
        scatter_ax_k<<<(Nrows * 32 + 255) / 256, 256, 0, stream>>>(hlast, Ax, nw, p, Nrows);
    }
}

// Round 5
// 1343.081 us; speedup vs baseline: 7.5307x; 1.0288x over previous
//
#include <hip/hip_runtime.h>
#include <hip/hip_bf16.h>

#define T2 2048
#define H2 256
#define BT2 131072          // B*T = 64*2048
#define MAXP 4

typedef __attribute__((ext_vector_type(8))) short bf16x8;
typedef __attribute__((ext_vector_type(4))) float f32x4;
typedef unsigned short u16;

__device__ __forceinline__ u16 f2bf(float f) {
    union { float f; unsigned u; } v; v.f = f;
    unsigned r = (v.u + 0x7FFFu + ((v.u >> 16) & 1u)) >> 16;
    return (u16)r;
}
__device__ __forceinline__ void async16(const void* g, void* l) {
    __builtin_amdgcn_global_load_lds((const __attribute__((address_space(1))) void*)g,
                                     (__attribute__((address_space(3))) void*)l, 16, 0, 0);
}
__device__ __forceinline__ float frcp(float x) { return __builtin_amdgcn_rcpf(x); }
__device__ __forceinline__ float sig_f(float x) { return frcp(1.f + __expf(-x)); }
__device__ __forceinline__ float tanh_f(float x) {
    return 1.f - 2.f * frcp(__expf(2.f * x) + 1.f);
}

// f32 -> bf16 cast, 4 elems/thread
__global__ __launch_bounds__(256) void cast_bf16_k(
    const float* __restrict__ in, u16* __restrict__ out, int n4)
{
    const int i = blockIdx.x * 256 + threadIdx.x;
    if (i >= n4) return;
    const float4 v = ((const float4*)in)[i];
    ushort4 h;
    h.x = f2bf(v.x); h.y = f2bf(v.y); h.z = f2bf(v.z); h.w = f2bf(v.w);
    ((ushort4*)out)[i] = h;
}

// ---------------------------------------------------------------------------
// Pure-bf16 GEMM: C = op(A @ Bt^T + bias). A [M][K] bf16 row-major,
// Bt [N=256][K] bf16 (batch-strided by bsB). 128x128 tile, BK=64, 4 waves,
// 8-slot XOR-swizzled LDS, 2-phase prefetch (double-buffered LDS; stage
// K-tile t+1 before computing t; single barrier per K-step whose implicit
// vmcnt(0) drain overlaps the MFMA phase).
// mode 0: plain decode (bx=bid>>1, by=bid&1, bz=0)      [support GEMMs]
// mode 1: supertile XCD decode (4 bx x 4 (by,bz) per supertile, ~4MB
//         working set L2-resident per XCD)               [adj GEMMs, nwg=2048]
// ---------------------------------------------------------------------------
__global__ __launch_bounds__(256) void bgemm_k(
    const u16* __restrict__ A, const u16* __restrict__ Bt,
    const float* __restrict__ bias,
    u16* __restrict__ Ct, u16* __restrict__ Cx,
    int K, long long bsB, int relu, int mode)
{
    __shared__ __align__(16) u16 As[2][128][64];
    __shared__ __align__(16) u16 Bs[2][128][64];

    const int tid = threadIdx.x;
    const int wid = tid >> 6, lane = tid & 63;
    const int wr = wid >> 1, wc = wid & 1;

    int bx, by, bz;
    if (mode == 0) { bx = blockIdx.x >> 1; by = blockIdx.x & 1; bz = 0; }
    else {
        // supertile decode: XCD-chunked, 16 blocks per supertile
        const int xcd = blockIdx.x & 7, loc = blockIdx.x >> 3;   // loc 0..255
        const int s = loc >> 4, w = loc & 15;                    // 16 st/XCD
        const int sg = xcd * 16 + s;                             // 0..127
        const int pzg = sg >> 2, bxg = sg & 3;
        bx = bxg * 4 + (w >> 2);                                 // 0..15
        const int pzidx = pzg * 4 + (w & 3);                     // 0..127
        by = pzidx >> 6; bz = pzidx & 63;
    }
    const int row0 = bx * 128, col0 = by * 128;
    const u16* Bp = Bt + (long long)bz * bsB;

    // staging: thread covers rows srow+32s, physical slot tid&7 holds global
    // k-chunk (tid&7)^(srow&7)
    const int srow = tid >> 3;                   // 0..31
    const int skA = ((tid ^ srow) & 7) << 3;     // swizzled k-elem offset
    const u16* Ag = A + (size_t)(row0 + srow) * K + skA;
    const u16* Bg = Bp + (size_t)(col0 + srow) * K + skA;
    char* ldsA = (char*)&As[0][0][0];
    char* ldsB = (char*)&Bs[0][0][0];
    const int wb = wid << 10;

    f32x4 acc[4][4];
    #pragma unroll
    for (int i = 0; i < 4; ++i)
        #pragma unroll
        for (int q = 0; q < 4; ++q) acc[i][q] = (f32x4){0.f, 0.f, 0.f, 0.f};

    // prologue: stage K-tile 0 into buf 0
    #pragma unroll
    for (int s = 0; s < 4; ++s) {
        async16(Ag + (size_t)(s * 32) * K, ldsA + s * 4096 + wb);
        async16(Bg + (size_t)(s * 32) * K, ldsB + s * 4096 + wb);
    }
    __syncthreads();   // compiler emits vmcnt(0) drain before barrier

    int cur = 0;
    for (int k0 = 0; k0 < K; k0 += 64) {
        // phase 1: issue next-tile stage into buf cur^1
        if (k0 + 64 < K) {
            char* dA = ldsA + ((cur ^ 1) << 14);
            char* dB = ldsB + ((cur ^ 1) << 14);
            #pragma unroll
            for (int s = 0; s < 4; ++s) {
                async16(Ag + (size_t)(s * 32) * K + k0 + 64, dA + s * 4096 + wb);
                async16(Bg + (size_t)(s * 32) * K + k0 + 64, dB + s * 4096 + wb);
            }
        }
        // phase 2: compute current buffer
        char* rA = ldsA + (cur << 14);
        char* rB = ldsB + (cur << 14);
        const int mb = lane & 15, g = lane >> 4;
        #pragma unroll
        for (int kk = 0; kk < 2; ++kk) {
            bf16x8 a[4], b[4];
            #pragma unroll
            for (int i = 0; i < 4; ++i) {
                const int r = wr * 64 + i * 16 + mb;
                a[i] = *(const bf16x8*)(rA + r * 128 + ((((kk << 2) + g) ^ (r & 7)) << 4));
            }
            #pragma unroll
            for (int q = 0; q < 4; ++q) {
                const int r = wc * 64 + q * 16 + mb;
                b[q] = *(const bf16x8*)(rB + r * 128 + ((((kk << 2) + g) ^ (r & 7)) << 4));
            }
            #pragma unroll
            for (int i = 0; i < 4; ++i)
                #pragma unroll
                for (int q = 0; q < 4; ++q)
                    acc[i][q] = __builtin_amdgcn_mfma_f32_16x16x32_bf16(a[i], b[q], acc[i][q], 0, 0, 0);
        }
        __syncthreads();   // drains next-tile loads; frees cur for restaging
        cur ^= 1;
    }

    #pragma unroll
    for (int i = 0; i < 4; ++i) {
        const int rl = wr * 64 + i * 16 + ((lane >> 4) << 2);
        const int grow = row0 + rl;
        #pragma unroll
        for (int q = 0; q < 4; ++q) {
            const int col = col0 + wc * 64 + q * 16 + (lane & 15);
            f32x4 v = acc[i][q];
            if (bias) {
                const float bv = bias[col];
                v[0] += bv; v[1] += bv; v[2] += bv; v[3] += bv;
            }
            if (relu) {
                v[0] = fmaxf(v[0], 0.f); v[1] = fmaxf(v[1], 0.f);
                v[2] = fmaxf(v[2], 0.f); v[3] = fmaxf(v[3], 0.f);
            }
            if (Ct) {  // bf16 transposed [b][col][t], t-block of 4
                ushort4 pk;
                pk.x = f2bf(v[0]); pk.y = f2bf(v[1]); pk.z = f2bf(v[2]); pk.w = f2bf(v[3]);
                *(ushort4*)(Ct + ((size_t)((grow >> 11) * 256 + col)) * 2048 + (grow & 2047)) = pk;
            }
            if (Cx) {  // bf16 mirror [bz][t][col]
                #pragma unroll
                for (int r = 0; r < 4; ++r)
                    Cx[((size_t)bz * 2048 + grow + r) * 256 + col] = f2bf(v[r]);
            }
        }
    }
}

// ---------------------------------------------------------------------------
// LSTM step: gates = gather(Ax) @ wih^T (+ hprev @ whh^T) + bias, fused
// pointwise. BK=64, 8-slot swizzle, 2-phase prefetch (dbuf LDS), XCD-chunked
// grid. Gate-major weights: frag q = gate q.
// ---------------------------------------------------------------------------
__global__ __launch_bounds__(256) void lstm_step_k(
    const u16* __restrict__ Ax, const u16* __restrict__ hprev,
    u16* __restrict__ hnext, float* __restrict__ outF, float* __restrict__ cst,
    const u16* __restrict__ wih, const u16* __restrict__ whh,
    const float* __restrict__ biasp, int nw, int p, int j, int cpx)
{
    __shared__ __align__(16) u16 As[2][128][64];
    __shared__ __align__(16) u16 Bs[2][128][64];

    const int tid = threadIdx.x;
    const int wid = tid >> 6, lane = tid & 63;
    const int wr = wid >> 1, wc = wid & 1;

    const int l = (blockIdx.x & 7) * cpx + (blockIdx.x >> 3);  // logical = x*8+y
    const int col0 = (l & 7) << 7;
    const int row0 = (l >> 3) << 7;
    const int first = (j == 0), last = (j == p - 1);

    const int srow = tid >> 3;
    const int skA = ((tid ^ srow) & 7) << 3;
    const unsigned unw = (unsigned)nw;

    const u16* axp[4];
    const u16* hpp[4];
    size_t wrow[4];
    #pragma unroll
    for (int s = 0; s < 4; ++s) {
        const int r = srow + 32 * s;
        const int n = row0 + r;
        const unsigned b = (unsigned)n / unw;
        const int w = n - (int)b * nw;
        axp[s] = Ax + ((size_t)b * T2 + (size_t)w * p + j) * H2 + skA;
        hpp[s] = hprev ? hprev + (size_t)n * H2 + skA : nullptr;
        wrow[s] = (size_t)(col0 + r) * H2 + skA;
    }
    char* ldsA = (char*)&As[0][0][0];
    char* ldsB = (char*)&Bs[0][0][0];
    const int wb = wid << 10;

    f32x4 acc[4][4];
    #pragma unroll
    for (int i = 0; i < 4; ++i)
        #pragma unroll
        for (int q = 0; q < 4; ++q) acc[i][q] = (f32x4){0.f, 0.f, 0.f, 0.f};

    const int KT = first ? 256 : 512;

    // prologue: stage k0=0 into buf 0 (always x-part)
    #pragma unroll
    for (int s = 0; s < 4; ++s) {
        async16(axp[s], ldsA + s * 4096 + wb);
        async16(wih + wrow[s], ldsB + s * 4096 + wb);
    }
    __syncthreads();

    int cur = 0;
    for (int k0 = 0; k0 < KT; k0 += 64) {
        // phase 1: issue next-chunk stage into buf cur^1
        const int kn = k0 + 64;
        if (kn < KT) {
            char* dA = ldsA + ((cur ^ 1) << 14);
            char* dB = ldsB + ((cur ^ 1) << 14);
            if (kn < 256) {
                #pragma unroll
                for (int s = 0; s < 4; ++s) {
                    async16(axp[s] + kn, dA + s * 4096 + wb);
                    async16(wih + wrow[s] + kn, dB + s * 4096 + wb);
                }
            } else {
                const int kk = kn - 256;
                #pragma unroll
                for (int s = 0; s < 4; ++s) {
                    async16(hpp[s] + kk, dA + s * 4096 + wb);
                    async16(whh + wrow[s] + kk, dB + s * 4096 + wb);
                }
            }
        }
        // phase 2: compute current buffer
        char* rA = ldsA + (cur << 14);
        char* rB = ldsB + (cur << 14);
        const int mb = lane & 15, g = lane >> 4;
        #pragma unroll
        for (int kk = 0; kk < 2; ++kk) {
            bf16x8 a[4], b[4];
            #pragma unroll
            for (int i = 0; i < 4; ++i) {
                const int r = wr * 64 + i * 16 + mb;
                a[i] = *(const bf16x8*)(rA + r * 128 + ((((kk << 2) + g) ^ (r & 7)) << 4));
            }
            #pragma unroll
            for (int q = 0; q < 4; ++q) {
                const int r = wc * 64 + q * 16 + mb;
                b[q] = *(const bf16x8*)(rB + r * 128 + ((((kk << 2) + g) ^ (r & 7)) << 4));
            }
            #pragma unroll
            for (int i = 0; i < 4; ++i)
                #pragma unroll
                for (int q = 0; q < 4; ++q)
                    acc[i][q] = __builtin_amdgcn_mfma_f32_16x16x32_bf16(a[i], b[q], acc[i][q], 0, 0, 0);
        }
        __syncthreads();
        cur ^= 1;
    }

    // in-register pointwise epilogue: frag q = gate q (i,f,g,o)
    const int u = lane & 15;
    const int colb = col0 + wc * 64;
    const int hu = (colb >> 2) + u;
    float bq[4];
    #pragma unroll
    for (int q = 0; q < 4; ++q) bq[q] = biasp[colb + q * 16 + u];

    #pragma unroll
    for (int i = 0; i < 4; ++i) {
        const int rbase = row0 + wr * 64 + i * 16 + ((lane >> 4) << 2);
        #pragma unroll
        for (int r = 0; r < 4; ++r) {
            const int n = rbase + r;
            const float gi = acc[i][0][r] + bq[0];
            const float gf = acc[i][1][r] + bq[1];
            const float gg = acc[i][2][r] + bq[2];
            const float go = acc[i][3][r] + bq[3];
            const float si = sig_f(gi), sf = sig_f(gf), so = sig_f(go);
            const float tg = tanh_f(gg);
            const float cp = first ? 0.f : cst[(size_t)n * H2 + hu];
            const float cn = sf * cp + si * tg;
            const float hv = so * tanh_f(cn);
            hnext[(size_t)n * H2 + hu] = f2bf(hv);
            if (last) {
                const unsigned b = (unsigned)n / unw;
                const int w = n - (int)b * nw;
                outF[((size_t)b * T2 + (size_t)w * p + (p - 1)) * H2 + hu] = hv;
            } else {
                cst[(size_t)n * H2 + hu] = cn;
            }
        }
    }
}

// update mirror Ax at window-end positions from deferred hnext (bf16 copy)
__global__ __launch_bounds__(256) void scatter_ax_k(
    const u16* __restrict__ hs, u16* __restrict__ Ax, int nw, int p, int Nrows)
{
    const int idx = blockIdx.x * 256 + threadIdx.x;   // 16B per thread
    if (idx >= Nrows * 32) return;
    const int n = idx >> 5, c8 = (idx & 31) << 3;
    const unsigned b = (unsigned)n / (unsigned)nw;
    const int w = n - (int)b * nw;
    *(uint4*)(Ax + ((size_t)b * T2 + (size_t)w * p + (p - 1)) * H2 + c8) =
        *(const uint4*)(hs + (size_t)n * H2 + c8);
}

// Wg transpose+cast: out[n][k] = bf16(in[k][n]), 256x256
__global__ __launch_bounds__(256) void convT_k(const float* __restrict__ in, u16* __restrict__ out)
{
    const int idx = blockIdx.x * 256 + threadIdx.x;
    const int r = idx >> 8, c = idx & 255;
    out[(size_t)c * 256 + r] = f2bf(in[idx]);
}

// LSTM weight gate-major permute: wP[pass][n'][k], n' = (h>>4)*64+g*16+(h&15)
__global__ __launch_bounds__(256) void convW_k(
    const float* __restrict__ Wih, const float* __restrict__ Whh,
    u16* __restrict__ wih_p, u16* __restrict__ whh_p)
{
    const int idx = blockIdx.x * 256 + threadIdx.x;   // 4*1024*256 total
    const int pp = idx >> 18;
    const int np = (idx >> 8) & 1023;
    const int k = idx & 255;
    const int group = np >> 6, g = (np >> 4) & 3, uu = np & 15;
    const int hh = group * 16 + uu;
    const size_t src = (size_t)pp * 262144 + (size_t)(g * 256 + hh) * 256 + k;
    wih_p[idx] = f2bf(Wih[src]);
    whh_p[idx] = f2bf(Whh[src]);
}

__global__ __launch_bounds__(256) void convB_k(
    const float* __restrict__ bih, const float* __restrict__ bhh, float* __restrict__ bp)
{
    const int idx = blockIdx.x * 256 + threadIdx.x;   // 4096
    const int pp = idx >> 10, np = idx & 1023;
    const int group = np >> 6, g = (np >> 4) & 3, uu = np & 15;
    const int hh = group * 16 + uu;
    bp[idx] = bih[pp * 1024 + g * 256 + hh] + bhh[pp * 1024 + g * 256 + hh];
}

// ---------------------------------------------------------------------------
extern "C" void kernel_launch(void* const* d_in, const int* in_sizes, int n_in,
                              void* d_out, int out_size, void* d_ws, size_t ws_size,
                              hipStream_t stream)
{
    const float* x   = (const float*)d_in[0];
    const float* adj = (const float*)d_in[1];
    const float* Wg0 = (const float*)d_in[2];
    const float* bg0 = (const float*)d_in[3];
    const float* Wg1 = (const float*)d_in[4];
    const float* bg1 = (const float*)d_in[5];
    const float* Wih = (const float*)d_in[6];
    const float* Whh = (const float*)d_in[7];
    const float* bih = (const float*)d_in[8];
    const float* bhh = (const float*)d_in[9];
    float* out = (float*)d_out;

    char* ws = (char*)d_ws;
    u16*   Ax   = (u16*)ws;                         // 67,108,864 B  bf16 mirror (h1 then h2)
    u16*   hsB  = (u16*)(ws + 67108864);            // 67,108,864 B  St (GCN) / hs0|hs1 (LSTM)
    u16*   hs0  = hsB;
    u16*   hs1  = (u16*)(ws + 67108864 + 33554432);
    float* cst  = (float*)(ws + 134217728);         // 67,108,864 B  f32 cell state
    u16*   xbf  = (u16*)(ws + 134217728);           // alias: x bf16 (dead before LSTM)
    char*  wreg = ws + 201326592;                   // 8,388,608 B region
    u16*   adjbf = (u16*)wreg;                      // GCN phase
    u16*   wihP  = (u16*)wreg;                      // LSTM phase (adjbf dead)
    u16*   whhP  = (u16*)(wreg + 2097152);
    float* bp    = (float*)(wreg + 4194304);
    u16*   wg0t  = (u16*)(ws + 209715200);          // 131,072 B
    u16*   wg1t  = (u16*)(ws + 209846272);          // 131,072 B
    u16*   St    = hsB;

    // ---- casts / weight prep ----
    cast_bf16_k<<<32768, 256, 0, stream>>>(x, xbf, 8388608);     // 33.5M elems
    cast_bf16_k<<<4096, 256, 0, stream>>>(adj, adjbf, 1048576);  // 4.2M elems
    convT_k<<<256, 256, 0, stream>>>(Wg0, wg0t);
    convT_k<<<256, 256, 0, stream>>>(Wg1, wg1t);

    // ---- GCN ----
    // support1^T = (x @ Wg0 + bg0)^T -> St
    bgemm_k<<<2048, 256, 0, stream>>>(xbf, wg0t, bg0, St, nullptr, 256, 0, 0, 0);
    // h1 = relu(adj @ support1) -> Ax mirror (bf16)
    bgemm_k<<<2048, 256, 0, stream>>>(adjbf, St, nullptr, nullptr, Ax, 2048,
                                      (long long)256 * 2048, 1, 1);
    // support2^T = (h1 @ Wg1 + bg1)^T -> St
    bgemm_k<<<2048, 256, 0, stream>>>(Ax, wg1t, bg1, St, nullptr, 256, 0, 0, 0);
    // h2 = relu(adj @ support2) -> Ax mirror (out fully overwritten by p=1 pass)
    bgemm_k<<<2048, 256, 0, stream>>>(adjbf, St, nullptr, nullptr, Ax, 2048,
                                      (long long)256 * 2048, 1, 1);

    // ---- LSTM weights (adjbf region now dead) ----
    convW_k<<<4096, 256, 0, stream>>>(Wih, Whh, wihP, whhP);
    convB_k<<<16, 256, 0, stream>>>(bih, bhh, bp);

    // ---- skip-LSTM passes ----
    for (int p = 1; p <= MAXP; ++p) {
        const int nw = T2 / p;
        const int Nrows = 64 * nw;                  // 131072 / 65536 / 43648 / 32768
        const int cpx = Nrows / 128;                // logical x-tiles; nwg = cpx*8
        const u16* wihp = wihP + (size_t)(p - 1) * 262144;
        const u16* whhp = whhP + (size_t)(p - 1) * 262144;
        const float* bpp = bp + (size_t)(p - 1) * 1024;
        for (int j = 0; j < p; ++j) {
            u16* hn = (p == 1) ? hsB : ((j & 1) ? hs1 : hs0);
            const u16* hpv = (j == 0) ? nullptr : ((j & 1) ? hs0 : hs1);
            lstm_step_k<<<cpx * 8, 256, 0, stream>>>(
                Ax, hpv, hn, out, cst, wihp, whhp, bpp, nw, p, j, cpx);
        }
        const u16* hlast = (p == 1) ? hsB : (((p - 1) & 1) ? hs1 : hs0);
        scatter_ax_k<<<(Nrows * 32 + 255) / 256, 256, 0, stream>>>(hlast, Ax, nw, p, Nrows);
    }
}